// Round 1
// baseline (121.664 us; speedup 1.0000x reference)
//
#include <hip/hip_runtime.h>

#define S 512
#define H 128
#define NROW 4096   // B*S
#define TI 8

// ---------------- kernel 1: qp/kp projection ----------------
// qp[row][h] = sum_d query[row][d]*W1[h][d] + b1[h]
// kp[row][h] = sum_d key[row][d]  *W1[h][128+d]
__global__ __launch_bounds__(256) void proj_kernel(
    const float* __restrict__ query, const float* __restrict__ key,
    const float* __restrict__ W1, const float* __restrict__ b1,
    float* __restrict__ qp, float* __restrict__ kp)
{
  __shared__ float w1t[128][130];   // w1t[d][h] = W1[h][off+d]
  const int bid = blockIdx.x;       // 0..255
  const bool isq = bid < 128;
  const float* __restrict__ src = isq ? query : key;
  const int rbase = (isq ? bid : bid - 128) * 32;
  const int off = isq ? 0 : 128;
  const int tid = threadIdx.x;

  for (int idx = tid; idx < 128 * 32; idx += 256) {
    const int d4 = idx & 31, h = idx >> 5;
    const float4 v = *(const float4*)(W1 + h * 256 + off + d4 * 4);
    w1t[d4 * 4 + 0][h] = v.x;
    w1t[d4 * 4 + 1][h] = v.y;
    w1t[d4 * 4 + 2][h] = v.z;
    w1t[d4 * 4 + 3][h] = v.w;
  }
  __syncthreads();

  const int w = __builtin_amdgcn_readfirstlane(tid >> 6);
  const int lane = tid & 63;
  const int r0 = rbase + w * 8;

  float acc[8][2];
  float2 bv = make_float2(0.f, 0.f);
  if (isq) bv = *(const float2*)(b1 + 2 * lane);
  #pragma unroll
  for (int r = 0; r < 8; r++) { acc[r][0] = bv.x; acc[r][1] = bv.y; }

  for (int dc = 0; dc < 128; dc += 8) {
    float qs[8][8];                 // wave-uniform -> SGPRs via s_load
    #pragma unroll
    for (int r = 0; r < 8; r++) {
      const float* sp = src + (size_t)(r0 + r) * H + dc;
      #pragma unroll
      for (int u = 0; u < 8; u++) qs[r][u] = sp[u];
    }
    #pragma unroll
    for (int dd = 0; dd < 8; dd++) {
      const float2 wv = *(const float2*)&w1t[dc + dd][2 * lane];
      #pragma unroll
      for (int r = 0; r < 8; r++) {
        acc[r][0] = __builtin_fmaf(qs[r][dd], wv.x, acc[r][0]);
        acc[r][1] = __builtin_fmaf(qs[r][dd], wv.y, acc[r][1]);
      }
    }
  }
  float* __restrict__ dst = isq ? qp : kp;
  #pragma unroll
  for (int r = 0; r < 8; r++) {
    *(float2*)(dst + (size_t)(r0 + r) * H + 2 * lane) =
        make_float2(acc[r][0], acc[r][1]);
  }
}

// ---------------- kernel 2: scores + exp + AV (partials) ----------------
// grid: x = i-tile (4096/TI = 512), y = j-half (2). 256 threads = 4 waves.
// wave w owns 64 j's (lane = j); all waves share the TI q-rows.
__global__ __launch_bounds__(256) void attn_kernel(
    const float* __restrict__ qp, const float* __restrict__ kp,
    const float* __restrict__ value, const int* __restrict__ q_mask,
    const int* __restrict__ k_mask, const float* __restrict__ W2,
    const float* __restrict__ b2,
    float* __restrict__ nump, float* __restrict__ denp)
{
  __shared__ float aT[4][64][12];   // per-wave a bounce buffer
  __shared__ float numk[TI][132];
  __shared__ float denk[TI];

  const int it = blockIdx.x;          // 0..511
  const int jh = blockIdx.y;          // 0..1
  const int r0 = it * TI;             // global q-row base (uniform)
  const int b  = r0 >> 9;
  const int tid = threadIdx.x;
  const int w = __builtin_amdgcn_readfirstlane(tid >> 6);
  const int lane = tid & 63;
  const int jl = (jh << 8) + (w << 6) + lane;  // within-b key index
  const int jg = (b << 9) + jl;                // global key row
  const int km = k_mask[jg];
  const float* __restrict__ kprow = kp + (size_t)jg * H;
  const float b2v = b2[0];

  // ---- phase 1: s[i] for this lane's j ----
  float s[TI];
  #pragma unroll
  for (int i = 0; i < TI; i++) s[i] = 0.f;

  for (int hc = 0; hc < H; hc += 16) {
    float kr[16];
    #pragma unroll
    for (int u = 0; u < 4; u++) {
      const float4 v4 = *(const float4*)(kprow + hc + u * 4);
      kr[u*4+0] = v4.x; kr[u*4+1] = v4.y; kr[u*4+2] = v4.z; kr[u*4+3] = v4.w;
    }
    float w2r[16];                    // uniform -> SGPR
    #pragma unroll
    for (int u = 0; u < 16; u++) w2r[u] = W2[hc + u];
    #pragma unroll
    for (int i = 0; i < TI; i++) {
      const float* __restrict__ qrow = qp + (size_t)(r0 + i) * H + hc; // uniform
      #pragma unroll
      for (int u = 0; u < 16; u++) {
        float t = fmaxf(qrow[u] + kr[u], 0.f);
        s[i] = __builtin_fmaf(t, w2r[u], s[i]);
      }
    }
  }

  // ---- mask + exp + den reduce ----
  float a[TI], den[TI];
  #pragma unroll
  for (int i = 0; i < TI; i++) {
    const int qm = q_mask[r0 + i];    // uniform
    a[i] = (km > 0 && qm > 0) ? __expf(s[i] + b2v) : 0.f;
  }
  #pragma unroll
  for (int i = 0; i < TI; i++) {
    float d = a[i];
    #pragma unroll
    for (int m = 32; m >= 1; m >>= 1) d += __shfl_xor(d, m, 64);
    den[i] = d;
  }
  #pragma unroll
  for (int i = 0; i < TI; i++) aT[w][lane][i] = a[i];
  __syncthreads();

  // ---- phase 2: num[i][h] += a[i][j]*v[j][h] over this wave's 64 j ----
  const int lj = lane >> 5, lh = lane & 31;   // lj: j-parity, lh*4: h2 window
  float nr[TI][4];
  #pragma unroll
  for (int i = 0; i < TI; i++) { nr[i][0]=0.f; nr[i][1]=0.f; nr[i][2]=0.f; nr[i][3]=0.f; }
  const float* __restrict__ vbase =
      value + ((size_t)b * S + (jh << 8) + (w << 6)) * H;

  for (int js = 0; js < 32; js++) {
    const int j = js * 2 + lj;
    const float4 vv = *(const float4*)(vbase + (size_t)j * H + lh * 4);
    float av[TI];
    { const float4 t0 = *(const float4*)&aT[w][j][0];
      const float4 t1 = *(const float4*)&aT[w][j][4];
      av[0]=t0.x; av[1]=t0.y; av[2]=t0.z; av[3]=t0.w;
      av[4]=t1.x; av[5]=t1.y; av[6]=t1.z; av[7]=t1.w; }
    #pragma unroll
    for (int i = 0; i < TI; i++) {
      nr[i][0] = __builtin_fmaf(av[i], vv.x, nr[i][0]);
      nr[i][1] = __builtin_fmaf(av[i], vv.y, nr[i][1]);
      nr[i][2] = __builtin_fmaf(av[i], vv.z, nr[i][2]);
      nr[i][3] = __builtin_fmaf(av[i], vv.w, nr[i][3]);
    }
  }
  #pragma unroll
  for (int i = 0; i < TI; i++) {
    #pragma unroll
    for (int k = 0; k < 4; k++) nr[i][k] += __shfl_xor(nr[i][k], 32, 64);
  }

  // ---- cross-wave accumulate in LDS (deterministic rounds) ----
  for (int r = 0; r < 4; r++) {
    if (w == r) {
      if (lj == 0) {
        #pragma unroll
        for (int i = 0; i < TI; i++) {
          float4* p = (float4*)&numk[i][lh * 4];
          if (r == 0) {
            *p = make_float4(nr[i][0], nr[i][1], nr[i][2], nr[i][3]);
          } else {
            float4 t = *p;
            t.x += nr[i][0]; t.y += nr[i][1]; t.z += nr[i][2]; t.w += nr[i][3];
            *p = t;
          }
        }
      }
      if (lane == 0) {
        #pragma unroll
        for (int i = 0; i < TI; i++)
          denk[i] = (r == 0) ? den[i] : denk[i] + den[i];
      }
    }
    __syncthreads();
  }

  // ---- store partials (deterministic, no atomics) ----
  {
    const int i = tid >> 5, seg = tid & 31;
    const float4 v = *(const float4*)&numk[i][seg * 4];
    float* dst = nump + ((size_t)jh * NROW + (size_t)(r0 + i)) * H + seg * 4;
    *(float4*)dst = v;
    if (tid < TI) denp[jh * NROW + r0 + tid] = denk[tid];
  }
}

// ---------------- kernel 3: finalize ----------------
__global__ __launch_bounds__(256) void finalize_kernel(
    const float* __restrict__ nump, const float* __restrict__ denp,
    float* __restrict__ out)
{
  const int idx = blockIdx.x * 256 + threadIdx.x;  // float4 units, 131072 total
  const int row = idx >> 5;
  const float4 a = *(const float4*)(nump + (size_t)idx * 4);
  const float4 c = *(const float4*)(nump + (size_t)NROW * H + (size_t)idx * 4);
  const float d = denp[row] + denp[NROW + row];
  const float inv = 1.f / fmaxf(d, 2e-15f);
  float4 o;
  o.x = (a.x + c.x) * inv; o.y = (a.y + c.y) * inv;
  o.z = (a.z + c.z) * inv; o.w = (a.w + c.w) * inv;
  *(float4*)(out + (size_t)idx * 4) = o;
}

extern "C" void kernel_launch(void* const* d_in, const int* in_sizes, int n_in,
                              void* d_out, int out_size, void* d_ws, size_t ws_size,
                              hipStream_t stream)
{
  (void)in_sizes; (void)n_in; (void)out_size; (void)ws_size;
  const float* query  = (const float*)d_in[0];
  const float* key    = (const float*)d_in[1];
  const float* value  = (const float*)d_in[2];
  const int*   q_mask = (const int*)d_in[3];
  const int*   k_mask = (const int*)d_in[4];
  const float* W1     = (const float*)d_in[5];
  const float* b1     = (const float*)d_in[6];
  const float* W2     = (const float*)d_in[7];
  const float* b2     = (const float*)d_in[8];
  float* out = (float*)d_out;

  float* ws   = (float*)d_ws;
  float* qp   = ws;                                  // [4096][128]
  float* kp   = ws + (size_t)NROW * H;               // [4096][128]
  float* nump = ws + (size_t)2 * NROW * H;           // [2][4096][128]
  float* denp = ws + (size_t)4 * NROW * H;           // [2][4096]

  proj_kernel<<<256, 256, 0, stream>>>(query, key, W1, b1, qp, kp);
  attn_kernel<<<dim3(512, 2), 256, 0, stream>>>(qp, kp, value, q_mask, k_mask,
                                                W2, b2, nump, denp);
  finalize_kernel<<<512, 256, 0, stream>>>(nump, denp, out);
}